// Round 6
// baseline (470.781 us; speedup 1.0000x reference)
//
#include <hip/hip_runtime.h>
#include <math.h>

#define M_ 4
#define A_ 256
#define RBF_ 64
#define F_ 32
#define H_ 32
#define SI_ 32
#define TF_ 128   // 4 tags * F

typedef __attribute__((ext_vector_type(8))) short bf16x8;
typedef __attribute__((ext_vector_type(4))) float f32x4;

__device__ __forceinline__ unsigned short f2bf(float f) {
  union { float f; unsigned u; } v; v.f = f;
  unsigned r = v.u + 0x7FFFu + ((v.u >> 16) & 1u);   // RNE bf16 (weights, one-time)
  return (unsigned short)(r >> 16);
}

// pack two fp32 -> two bf16 (round-half-up: +0x8000 then take hi16) in 3 VALU
__device__ __forceinline__ unsigned pack2bf(float lo, float hi) {
  union { float f; unsigned u; } a, b; a.f = lo; b.f = hi;
  return __builtin_amdgcn_perm(b.u + 0x8000u, a.u + 0x8000u, 0x07060302u);
}

__device__ __forceinline__ float sspf(float x) {
  // log(0.5*exp(x)+0.5) = softplus(x) - ln2, numerically stable
  return fmaxf(x, 0.f) + log1pf(expf(-fabsf(x))) - 0.6931471805599453f;
}

// ---------------------------------------------------------------------------
// Setup: collapse the two linear Dense layers per tag into one 64x32 map.
// ws layout: WcT bf16 [tf=128][k=64] (16384 B) | bc fp32[128] at +16384
//            | part fp32 [1024][2][352] at +32768 (2.88 MB).
// tf = tag*32 + f, tag order {00,01,10,11}.
// ---------------------------------------------------------------------------
__global__ __launch_bounds__(256) void combine_weights(
    const float* __restrict__ w1_00, const float* __restrict__ b1_00,
    const float* __restrict__ w2_00, const float* __restrict__ b2_00,
    const float* __restrict__ w1_01, const float* __restrict__ b1_01,
    const float* __restrict__ w2_01, const float* __restrict__ b2_01,
    const float* __restrict__ w1_10, const float* __restrict__ b1_10,
    const float* __restrict__ w2_10, const float* __restrict__ b2_10,
    const float* __restrict__ w1_11, const float* __restrict__ b1_11,
    const float* __restrict__ w2_11, const float* __restrict__ b2_11,
    unsigned short* __restrict__ wsT, float* __restrict__ bcw)
{
  const float* w1s[4] = {w1_00, w1_01, w1_10, w1_11};
  const float* b1s[4] = {b1_00, b1_01, b1_10, b1_11};
  const float* w2s[4] = {w2_00, w2_01, w2_10, w2_11};
  const float* b2s[4] = {b2_00, b2_01, b2_10, b2_11};
  int tid = blockIdx.x * 256 + threadIdx.x;    // 0..8191
  int k   = tid >> 7;
  int tf  = tid & 127;
  int tag = tf >> 5, f = tf & 31;
  const float* w1 = w1s[tag];
  const float* w2 = w2s[tag];
  float s = 0.f;
  for (int h = 0; h < H_; ++h) s += w1[k * H_ + h] * w2[h * F_ + f];
  wsT[tf * 64 + k] = f2bf(s);                  // transposed for B-frag loads
  if (tid < TF_) {
    const float* b1 = b1s[tag];
    const float* b2 = b2s[tag];
    float sb = b2[f];
    for (int h = 0; h < H_; ++h) sb += b1[h] * w2[h * F_ + f];
    bcw[tf] = sb;                              // bias stays fp32
  }
}

// ---------------------------------------------------------------------------
// Partial-conv kernel: one block per (m,a,half) -- grid 2048, 4 waves.
//  half owns b in [half*128, half*128+128) = 8 b-tiles.
//  Wave role: which = w&1; pairsel = ((w>>1)^blockIdx)&1 selects tag pair
//  {00,11} (0) or {01,10} (1); Wc fragments + bias in registers.
//  GEMM via mfma_f32_16x16x32_bf16; C-frag row(b)=quad*4+reg, col=lane&15.
//  feat/vec double-buffered one b-tile ahead. Quad-copy reduce via shfl_xor
//  (copies sit at lanes n+16q of the same wave) -- NO LDS reduce, 1 barrier.
//  Partial sums (352 per half) written to ws; si_epilogue sums halves.
// LDS: sA [128][72] bf16 = 18432 B -> 8 blocks/CU; VGPR<=64 -> 32 waves/CU.
// ---------------------------------------------------------------------------
__global__ __launch_bounds__(256, 8) void conv_partial(
    const float* __restrict__ image, const float* __restrict__ vectors,
    const float* __restrict__ feat0, const float* __restrict__ feat1,
    const unsigned short* __restrict__ wsT, const float* __restrict__ bcw,
    float* __restrict__ part)
{
  __shared__ __align__(16) unsigned short sA[128 * 72];   // 18432 B

  const int t    = threadIdx.x;
  const int bid  = blockIdx.x;
  const int ma   = bid >> 1;        // m*256 + a
  const int half = bid & 1;
  const int m    = ma >> 8;
  const int w    = t >> 6;
  const int l    = t & 63;
  const int n    = l & 15;
  const int quad = l >> 4;
  const int which   = w & 1;
  const int pairsel = ((w >> 1) ^ bid) & 1;
  const int tagA = pairsel ? 1 : 0;       // pair0: {00,11}, pair1: {01,10}
  const int tagB = pairsel ? 2 : 3;
  const int ctA  = tagA * 2 + which;
  const int ctB  = tagB * 2 + which;
  const int f    = which * 16 + n;        // feature column this lane owns

  // ---- Wc fragments + bias into registers (global, L2-resident) ----
  const unsigned short* wrA = wsT + (ctA * 16 + n) * 64 + quad * 8;
  const unsigned short* wrB = wsT + (ctB * 16 + n) * 64 + quad * 8;
  const bf16x8 wA0 = *(const bf16x8*)(wrA);
  const bf16x8 wA1 = *(const bf16x8*)(wrA + 32);
  const bf16x8 wB0 = *(const bf16x8*)(wrB);
  const bf16x8 wB1 = *(const bf16x8*)(wrB + 32);
  const float  bcA = bcw[ctA * 16 + n];
  const float  bcB = bcw[ctB * 16 + n];

  // ---- stage this half's image rows (128 b x 64 rbf) to LDS as bf16 ----
  const float* imgH = image + ((size_t)ma * A_ + half * 128) * RBF_;
  #pragma unroll
  for (int i = 0; i < 4; ++i) {
    int g = t + 256 * i;            // 0..1023 groups of 8 elems
    int r = g >> 3, c8 = g & 7;
    const float* src = imgH + r * RBF_ + c8 * 8;
    float4 v0 = *(const float4*)(src);
    float4 v1 = *(const float4*)(src + 4);
    uint4 pk;
    pk.x = pack2bf(v0.x, v0.y);
    pk.y = pack2bf(v0.z, v0.w);
    pk.z = pack2bf(v1.x, v1.y);
    pk.w = pack2bf(v1.z, v1.w);
    *(uint4*)&sA[r * 72 + c8 * 8] = pk;
  }

  // ---- lane-private operand pointers (global b) ----
  const float* p0 = feat0 + (size_t)(m * A_) * F_ + f;          // + b*F_
  const float* p1 = feat1 + ((size_t)(m * A_) * F_ + f) * 3;    // + b*96
  const float* pv = vectors + (size_t)ma * A_ * 3;              // + b*3

  float ft0[2][4], gg[2][3][4], vv[2][3][4];
  float pS0 = 0.f, pS1 = 0.f, pV0 = 0.f, pV1 = 0.f, pV2 = 0.f;
  float pW0 = 0.f, pW1 = 0.f, pW2 = 0.f;

#define PF(BUF, BT) { \
    const int b0 = half * 128 + (BT) * 16 + quad * 4; \
    _Pragma("unroll") \
    for (int r = 0; r < 4; ++r) { \
      ft0[BUF][r] = p0[(b0 + r) * F_]; \
      const float* fp = p1 + (size_t)(b0 + r) * (F_ * 3); \
      gg[BUF][0][r] = fp[0]; gg[BUF][1][r] = fp[1]; gg[BUF][2][r] = fp[2]; \
      const float* vp = pv + (b0 + r) * 3; \
      vv[BUF][0][r] = vp[0]; vv[BUF][1][r] = vp[1]; vv[BUF][2][r] = vp[2]; \
    } }

#define BODY(BT, BUF) { \
    const int brow = (BT) * 16; \
    const bf16x8 a0 = *(const bf16x8*)&sA[(brow + n) * 72 + quad * 8]; \
    const bf16x8 a1 = *(const bf16x8*)&sA[(brow + n) * 72 + 32 + quad * 8]; \
    f32x4 accA = {bcA, bcA, bcA, bcA}; \
    f32x4 accB = {bcB, bcB, bcB, bcB}; \
    accA = __builtin_amdgcn_mfma_f32_16x16x32_bf16(a0, wA0, accA, 0, 0, 0); \
    accA = __builtin_amdgcn_mfma_f32_16x16x32_bf16(a1, wA1, accA, 0, 0, 0); \
    accB = __builtin_amdgcn_mfma_f32_16x16x32_bf16(a0, wB0, accB, 0, 0, 0); \
    accB = __builtin_amdgcn_mfma_f32_16x16x32_bf16(a1, wB1, accB, 0, 0, 0); \
    if (pairsel == 0) {            /* accA -> tag00, accB -> tag11 */ \
      _Pragma("unroll") \
      for (int r = 0; r < 4; ++r) pS0 += accA[r] * ft0[BUF][r]; \
      _Pragma("unroll") \
      for (int r = 0; r < 4; ++r) { \
        const float Rr = accB[r]; \
        const float gx = gg[BUF][0][r], gy = gg[BUF][1][r], gz = gg[BUF][2][r]; \
        const float ux = vv[BUF][0][r], uy = vv[BUF][1][r], uz = vv[BUF][2][r]; \
        pS1 += Rr * (ux * gx + uy * gy + uz * gz); \
        pV0 += Rr * (uy * gz - uz * gy); \
        pV1 += Rr * (uz * gx - ux * gz); \
        pV2 += Rr * (ux * gy - uy * gx); \
      } \
    } else {                       /* accA -> tag01, accB -> tag10 */ \
      _Pragma("unroll") \
      for (int r = 0; r < 4; ++r) { \
        const float s = accA[r] * ft0[BUF][r]; \
        pV0 += vv[BUF][0][r] * s; \
        pV1 += vv[BUF][1][r] * s; \
        pV2 += vv[BUF][2][r] * s; \
        const float Rb = accB[r]; \
        pW0 += Rb * gg[BUF][0][r]; \
        pW1 += Rb * gg[BUF][1][r]; \
        pW2 += Rb * gg[BUF][2][r]; \
      } \
    } }

  PF(0, 0)
  __syncthreads();

  #pragma unroll 1
  for (int bth = 0; bth < 4; ++bth) {
    const int bt0 = bth * 2;
    PF(1, bt0 + 1)        // issue next-tile loads before consuming current
    BODY(bt0, 0)
    if (bth < 3) PF(0, bt0 + 2)
    BODY(bt0 + 1, 1)
  }

  // ---- reduce the 4 quad-copies via cross-lane butterfly, write partials ----
#define QRED(x) { x += __shfl_xor(x, 16); x += __shfl_xor(x, 32); }
  float* dst = part + ((size_t)ma * 2 + half) * 352;
  // slots (cat order): out000: f | out110: 32+f | out011: 64+f*3+d
  //                    out101: 160+f*3+d | out111: 256+f*3+d
  if (pairsel == 0) {
    QRED(pS0) QRED(pS1) QRED(pV0) QRED(pV1) QRED(pV2)
    if (quad == 0) {
      dst[f]                 = pS0;
      dst[32 + f]            = pS1;
      dst[256 + f * 3 + 0]   = pV0;
      dst[256 + f * 3 + 1]   = pV1;
      dst[256 + f * 3 + 2]   = pV2;
    }
  } else {
    QRED(pV0) QRED(pV1) QRED(pV2) QRED(pW0) QRED(pW1) QRED(pW2)
    if (quad == 0) {
      dst[64 + f * 3 + 0]    = pV0;
      dst[64 + f * 3 + 1]    = pV1;
      dst[64 + f * 3 + 2]    = pV2;
      dst[160 + f * 3 + 0]   = pW0;
      dst[160 + f * 3 + 1]   = pW1;
      dst[160 + f * 3 + 2]   = pW2;
    }
  }
}

// ---------------------------------------------------------------------------
// Epilogue: one block per (m,a), 64 threads. Sum the two halves' partials,
// then self-interaction + equivariant activation.
// ---------------------------------------------------------------------------
__global__ __launch_bounds__(64) void si_epilogue(
    const float* __restrict__ part,
    const float* __restrict__ w_si0, const float* __restrict__ w_si1,
    const float* __restrict__ b_act0, const float* __restrict__ b_act1,
    float* __restrict__ out)
{
  __shared__ float cat[352];
  const int ma = blockIdx.x;
  const int t  = threadIdx.x;
  const float* pA = part + (size_t)ma * 704;
  const float* pB = pA + 352;
  for (int s = t; s < 352; s += 64) cat[s] = pA[s] + pB[s];
  __syncthreads();

  const int outBase = ma * SI_;
  if (t < 32) {
    const float* wr = w_si0 + t * 64;
    float s = 0.f;
    #pragma unroll 8
    for (int ff = 0; ff < 64; ++ff) s += cat[ff] * wr[ff];
    s += b_act0[t];
    out[outBase + t] = sspf(s);
  } else {
    int g = t - 32;
    const float* wr = w_si1 + g * 96;
    float s0 = 0.f, s1 = 0.f, s2 = 0.f;
    #pragma unroll 8
    for (int ff = 0; ff < 96; ++ff) {
      float wv = wr[ff];
      s0 += cat[64 + ff * 3 + 0] * wv;
      s1 += cat[64 + ff * 3 + 1] * wv;
      s2 += cat[64 + ff * 3 + 2] * wv;
    }
    float n2 = s0 * s0 + s1 * s1 + s2 * s2;
    float n1 = sqrtf(fmaxf(n2, 1e-7f));     // norm_with_epsilon, EPS=1e-7
    float a1 = sspf(n1 + b_act1[g]);
    float sc = a1 / n1;
    int ob = M_ * A_ * SI_ + (outBase + g) * 3;   // o0 is 32768 floats
    out[ob + 0] = s0 * sc;
    out[ob + 1] = s1 * sc;
    out[ob + 2] = s2 * sc;
  }
}

extern "C" void kernel_launch(void* const* d_in, const int* in_sizes, int n_in,
                              void* d_out, int out_size, void* d_ws, size_t ws_size,
                              hipStream_t stream) {
  const float* image   = (const float*)d_in[0];
  const float* vectors = (const float*)d_in[1];
  const float* feat0   = (const float*)d_in[2];
  const float* feat1   = (const float*)d_in[3];
  const float* w_si0   = (const float*)d_in[20];
  const float* w_si1   = (const float*)d_in[21];
  const float* b_act0  = (const float*)d_in[22];
  const float* b_act1  = (const float*)d_in[23];
  unsigned short* wsT = (unsigned short*)d_ws;           // 128*64 bf16 = 16384 B
  float* bcw  = (float*)((char*)d_ws + 16384);           // 128 f32
  float* part = (float*)((char*)d_ws + 32768);           // 1024*2*352 f32
  float* out  = (float*)d_out;

  combine_weights<<<32, 256, 0, stream>>>(
      (const float*)d_in[4],  (const float*)d_in[5],
      (const float*)d_in[6],  (const float*)d_in[7],
      (const float*)d_in[8],  (const float*)d_in[9],
      (const float*)d_in[10], (const float*)d_in[11],
      (const float*)d_in[12], (const float*)d_in[13],
      (const float*)d_in[14], (const float*)d_in[15],
      (const float*)d_in[16], (const float*)d_in[17],
      (const float*)d_in[18], (const float*)d_in[19],
      wsT, bcw);

  conv_partial<<<2 * M_ * A_, 256, 0, stream>>>(
      image, vectors, feat0, feat1, wsT, bcw, part);

  si_epilogue<<<M_ * A_, 64, 0, stream>>>(
      part, w_si0, w_si1, b_act0, b_act1, out);
}

// Round 7
// 207.024 us; speedup vs baseline: 2.2740x; 2.2740x over previous
//
#include <hip/hip_runtime.h>
#include <math.h>

#define M_ 4
#define A_ 256
#define RBF_ 64
#define F_ 32
#define H_ 32
#define SI_ 32
#define TF_ 128   // 4 tags * F

typedef __attribute__((ext_vector_type(8))) short bf16x8;
typedef __attribute__((ext_vector_type(4))) float f32x4;

__device__ __forceinline__ unsigned short f2bf(float f) {
  union { float f; unsigned u; } v; v.f = f;
  unsigned r = v.u + 0x7FFFu + ((v.u >> 16) & 1u);   // RNE bf16 (weights, one-time)
  return (unsigned short)(r >> 16);
}

// pack two fp32 -> two bf16 (round-half-up: +0x8000 then take hi16) in 3 VALU
__device__ __forceinline__ unsigned pack2bf(float lo, float hi) {
  union { float f; unsigned u; } a, b; a.f = lo; b.f = hi;
  return __builtin_amdgcn_perm(b.u + 0x8000u, a.u + 0x8000u, 0x07060302u);
}

__device__ __forceinline__ float sspf(float x) {
  // log(0.5*exp(x)+0.5) = softplus(x) - ln2, numerically stable
  return fmaxf(x, 0.f) + log1pf(expf(-fabsf(x))) - 0.6931471805599453f;
}

// ---------------------------------------------------------------------------
// Setup: collapse the two linear Dense layers per tag into one 64x32 map.
// ws layout: WcT bf16 [tf=128][k=64] (16384 B) | bc fp32[128] at +16384
//            | part fp32 [1024][2][352] at +32768 (2.88 MB).
// tf = tag*32 + f, tag order {00,01,10,11}.
// ---------------------------------------------------------------------------
__global__ __launch_bounds__(256) void combine_weights(
    const float* __restrict__ w1_00, const float* __restrict__ b1_00,
    const float* __restrict__ w2_00, const float* __restrict__ b2_00,
    const float* __restrict__ w1_01, const float* __restrict__ b1_01,
    const float* __restrict__ w2_01, const float* __restrict__ b2_01,
    const float* __restrict__ w1_10, const float* __restrict__ b1_10,
    const float* __restrict__ w2_10, const float* __restrict__ b2_10,
    const float* __restrict__ w1_11, const float* __restrict__ b1_11,
    const float* __restrict__ w2_11, const float* __restrict__ b2_11,
    unsigned short* __restrict__ wsT, float* __restrict__ bcw)
{
  const float* w1s[4] = {w1_00, w1_01, w1_10, w1_11};
  const float* b1s[4] = {b1_00, b1_01, b1_10, b1_11};
  const float* w2s[4] = {w2_00, w2_01, w2_10, w2_11};
  const float* b2s[4] = {b2_00, b2_01, b2_10, b2_11};
  int tid = blockIdx.x * 256 + threadIdx.x;    // 0..8191
  int k   = tid >> 7;
  int tf  = tid & 127;
  int tag = tf >> 5, f = tf & 31;
  const float* w1 = w1s[tag];
  const float* w2 = w2s[tag];
  float s = 0.f;
  for (int h = 0; h < H_; ++h) s += w1[k * H_ + h] * w2[h * F_ + f];
  wsT[tf * 64 + k] = f2bf(s);                  // transposed for B-frag loads
  if (tid < TF_) {
    const float* b1 = b1s[tag];
    const float* b2 = b2s[tag];
    float sb = b2[f];
    for (int h = 0; h < H_; ++h) sb += b1[h] * w2[h * F_ + f];
    bcw[tf] = sb;                              // bias stays fp32
  }
}

// ---------------------------------------------------------------------------
// Partial-conv kernel: one block per (m,a,half) -- grid 2048, 4 waves.
//  half owns b in [half*128, half*128+128) = 8 b-tiles.
//  Wave role: which = w&1; pairsel = ((w>>1)^blockIdx)&1 selects tag pair
//  {00,11} (0) or {01,10} (1); Wc fragments + bias in registers.
//  GEMM via mfma_f32_16x16x32_bf16; C-frag row(b)=quad*4+reg, col=lane&15.
//  feat/vec double-buffered one b-tile ahead. Quad-copy reduce via shfl_xor
//  (copies sit at lanes n+16q of the same wave) -- NO LDS reduce, 1 barrier.
//  Partial sums (352 per half) written to ws; si_epilogue sums halves.
// LDS: sA [128][72] bf16 = 18432 B.
// __launch_bounds__(256,4): VGPR cap 128; body fits at ~64 VGPR (R5 measured)
// -> occupancy min(LDS 8, VGPR 512/64=8 waves/SIMD) = 8 blocks/CU natural.
// DO NOT set min-waves=8: that hard-caps VGPR at 64 and spills (R6: 1.3 GB).
// ---------------------------------------------------------------------------
__global__ __launch_bounds__(256, 4) void conv_partial(
    const float* __restrict__ image, const float* __restrict__ vectors,
    const float* __restrict__ feat0, const float* __restrict__ feat1,
    const unsigned short* __restrict__ wsT, const float* __restrict__ bcw,
    float* __restrict__ part)
{
  __shared__ __align__(16) unsigned short sA[128 * 72];   // 18432 B

  const int t    = threadIdx.x;
  const int bid  = blockIdx.x;
  const int ma   = bid >> 1;        // m*256 + a
  const int half = bid & 1;
  const int m    = ma >> 8;
  const int w    = t >> 6;
  const int l    = t & 63;
  const int n    = l & 15;
  const int quad = l >> 4;
  const int which   = w & 1;
  const int pairsel = ((w >> 1) ^ bid) & 1;
  const int tagA = pairsel ? 1 : 0;       // pair0: {00,11}, pair1: {01,10}
  const int tagB = pairsel ? 2 : 3;
  const int ctA  = tagA * 2 + which;
  const int ctB  = tagB * 2 + which;
  const int f    = which * 16 + n;        // feature column this lane owns

  // ---- Wc fragments + bias into registers (global, L2-resident) ----
  const unsigned short* wrA = wsT + (ctA * 16 + n) * 64 + quad * 8;
  const unsigned short* wrB = wsT + (ctB * 16 + n) * 64 + quad * 8;
  const bf16x8 wA0 = *(const bf16x8*)(wrA);
  const bf16x8 wA1 = *(const bf16x8*)(wrA + 32);
  const bf16x8 wB0 = *(const bf16x8*)(wrB);
  const bf16x8 wB1 = *(const bf16x8*)(wrB + 32);
  const float  bcA = bcw[ctA * 16 + n];
  const float  bcB = bcw[ctB * 16 + n];

  // ---- stage this half's image rows (128 b x 64 rbf) to LDS as bf16 ----
  const float* imgH = image + ((size_t)ma * A_ + half * 128) * RBF_;
  #pragma unroll
  for (int i = 0; i < 4; ++i) {
    int g = t + 256 * i;            // 0..1023 groups of 8 elems
    int r = g >> 3, c8 = g & 7;
    const float* src = imgH + r * RBF_ + c8 * 8;
    float4 v0 = *(const float4*)(src);
    float4 v1 = *(const float4*)(src + 4);
    uint4 pk;
    pk.x = pack2bf(v0.x, v0.y);
    pk.y = pack2bf(v0.z, v0.w);
    pk.z = pack2bf(v1.x, v1.y);
    pk.w = pack2bf(v1.z, v1.w);
    *(uint4*)&sA[r * 72 + c8 * 8] = pk;
  }

  // ---- lane-private operand pointers (global b) ----
  const float* p0 = feat0 + (size_t)(m * A_) * F_ + f;          // + b*F_
  const float* p1 = feat1 + ((size_t)(m * A_) * F_ + f) * 3;    // + b*96
  const float* pv = vectors + (size_t)ma * A_ * 3;              // + b*3

  float ft0[2][4], gg[2][3][4], vv[2][3][4];
  float pS0 = 0.f, pS1 = 0.f, pV0 = 0.f, pV1 = 0.f, pV2 = 0.f;
  float pW0 = 0.f, pW1 = 0.f, pW2 = 0.f;

#define PF(BUF, BT) { \
    const int b0 = half * 128 + (BT) * 16 + quad * 4; \
    _Pragma("unroll") \
    for (int r = 0; r < 4; ++r) { \
      ft0[BUF][r] = p0[(b0 + r) * F_]; \
      const float* fp = p1 + (size_t)(b0 + r) * (F_ * 3); \
      gg[BUF][0][r] = fp[0]; gg[BUF][1][r] = fp[1]; gg[BUF][2][r] = fp[2]; \
      const float* vp = pv + (b0 + r) * 3; \
      vv[BUF][0][r] = vp[0]; vv[BUF][1][r] = vp[1]; vv[BUF][2][r] = vp[2]; \
    } }

#define BODY(BT, BUF) { \
    const int brow = (BT) * 16; \
    const bf16x8 a0 = *(const bf16x8*)&sA[(brow + n) * 72 + quad * 8]; \
    const bf16x8 a1 = *(const bf16x8*)&sA[(brow + n) * 72 + 32 + quad * 8]; \
    f32x4 accA = {bcA, bcA, bcA, bcA}; \
    f32x4 accB = {bcB, bcB, bcB, bcB}; \
    accA = __builtin_amdgcn_mfma_f32_16x16x32_bf16(a0, wA0, accA, 0, 0, 0); \
    accA = __builtin_amdgcn_mfma_f32_16x16x32_bf16(a1, wA1, accA, 0, 0, 0); \
    accB = __builtin_amdgcn_mfma_f32_16x16x32_bf16(a0, wB0, accB, 0, 0, 0); \
    accB = __builtin_amdgcn_mfma_f32_16x16x32_bf16(a1, wB1, accB, 0, 0, 0); \
    if (pairsel == 0) {            /* accA -> tag00, accB -> tag11 */ \
      _Pragma("unroll") \
      for (int r = 0; r < 4; ++r) pS0 += accA[r] * ft0[BUF][r]; \
      _Pragma("unroll") \
      for (int r = 0; r < 4; ++r) { \
        const float Rr = accB[r]; \
        const float gx = gg[BUF][0][r], gy = gg[BUF][1][r], gz = gg[BUF][2][r]; \
        const float ux = vv[BUF][0][r], uy = vv[BUF][1][r], uz = vv[BUF][2][r]; \
        pS1 += Rr * (ux * gx + uy * gy + uz * gz); \
        pV0 += Rr * (uy * gz - uz * gy); \
        pV1 += Rr * (uz * gx - ux * gz); \
        pV2 += Rr * (ux * gy - uy * gx); \
      } \
    } else {                       /* accA -> tag01, accB -> tag10 */ \
      _Pragma("unroll") \
      for (int r = 0; r < 4; ++r) { \
        const float s = accA[r] * ft0[BUF][r]; \
        pV0 += vv[BUF][0][r] * s; \
        pV1 += vv[BUF][1][r] * s; \
        pV2 += vv[BUF][2][r] * s; \
        const float Rb = accB[r]; \
        pW0 += Rb * gg[BUF][0][r]; \
        pW1 += Rb * gg[BUF][1][r]; \
        pW2 += Rb * gg[BUF][2][r]; \
      } \
    } }

  PF(0, 0)
  __syncthreads();

  #pragma unroll 1
  for (int bth = 0; bth < 4; ++bth) {
    const int bt0 = bth * 2;
    PF(1, bt0 + 1)        // issue next-tile loads before consuming current
    BODY(bt0, 0)
    if (bth < 3) PF(0, bt0 + 2)
    BODY(bt0 + 1, 1)
  }

  // ---- reduce the 4 quad-copies via cross-lane butterfly, write partials ----
#define QRED(x) { x += __shfl_xor(x, 16); x += __shfl_xor(x, 32); }
  float* dst = part + ((size_t)ma * 2 + half) * 352;
  // slots (cat order): out000: f | out110: 32+f | out011: 64+f*3+d
  //                    out101: 160+f*3+d | out111: 256+f*3+d
  if (pairsel == 0) {
    QRED(pS0) QRED(pS1) QRED(pV0) QRED(pV1) QRED(pV2)
    if (quad == 0) {
      dst[f]                 = pS0;
      dst[32 + f]            = pS1;
      dst[256 + f * 3 + 0]   = pV0;
      dst[256 + f * 3 + 1]   = pV1;
      dst[256 + f * 3 + 2]   = pV2;
    }
  } else {
    QRED(pV0) QRED(pV1) QRED(pV2) QRED(pW0) QRED(pW1) QRED(pW2)
    if (quad == 0) {
      dst[64 + f * 3 + 0]    = pV0;
      dst[64 + f * 3 + 1]    = pV1;
      dst[64 + f * 3 + 2]    = pV2;
      dst[160 + f * 3 + 0]   = pW0;
      dst[160 + f * 3 + 1]   = pW1;
      dst[160 + f * 3 + 2]   = pW2;
    }
  }
}

// ---------------------------------------------------------------------------
// Epilogue: one block per (m,a), 64 threads. Sum the two halves' partials,
// then self-interaction + equivariant activation.
// ---------------------------------------------------------------------------
__global__ __launch_bounds__(64) void si_epilogue(
    const float* __restrict__ part,
    const float* __restrict__ w_si0, const float* __restrict__ w_si1,
    const float* __restrict__ b_act0, const float* __restrict__ b_act1,
    float* __restrict__ out)
{
  __shared__ float cat[352];
  const int ma = blockIdx.x;
  const int t  = threadIdx.x;
  const float* pA = part + (size_t)ma * 704;
  const float* pB = pA + 352;
  for (int s = t; s < 352; s += 64) cat[s] = pA[s] + pB[s];
  __syncthreads();

  const int outBase = ma * SI_;
  if (t < 32) {
    const float* wr = w_si0 + t * 64;
    float s = 0.f;
    #pragma unroll 8
    for (int ff = 0; ff < 64; ++ff) s += cat[ff] * wr[ff];
    s += b_act0[t];
    out[outBase + t] = sspf(s);
  } else {
    int g = t - 32;
    const float* wr = w_si1 + g * 96;
    float s0 = 0.f, s1 = 0.f, s2 = 0.f;
    #pragma unroll 8
    for (int ff = 0; ff < 96; ++ff) {
      float wv = wr[ff];
      s0 += cat[64 + ff * 3 + 0] * wv;
      s1 += cat[64 + ff * 3 + 1] * wv;
      s2 += cat[64 + ff * 3 + 2] * wv;
    }
    float n2 = s0 * s0 + s1 * s1 + s2 * s2;
    float n1 = sqrtf(fmaxf(n2, 1e-7f));     // norm_with_epsilon, EPS=1e-7
    float a1 = sspf(n1 + b_act1[g]);
    float sc = a1 / n1;
    int ob = M_ * A_ * SI_ + (outBase + g) * 3;   // o0 is 32768 floats
    out[ob + 0] = s0 * sc;
    out[ob + 1] = s1 * sc;
    out[ob + 2] = s2 * sc;
  }
}

extern "C" void kernel_launch(void* const* d_in, const int* in_sizes, int n_in,
                              void* d_out, int out_size, void* d_ws, size_t ws_size,
                              hipStream_t stream) {
  const float* image   = (const float*)d_in[0];
  const float* vectors = (const float*)d_in[1];
  const float* feat0   = (const float*)d_in[2];
  const float* feat1   = (const float*)d_in[3];
  const float* w_si0   = (const float*)d_in[20];
  const float* w_si1   = (const float*)d_in[21];
  const float* b_act0  = (const float*)d_in[22];
  const float* b_act1  = (const float*)d_in[23];
  unsigned short* wsT = (unsigned short*)d_ws;           // 128*64 bf16 = 16384 B
  float* bcw  = (float*)((char*)d_ws + 16384);           // 128 f32
  float* part = (float*)((char*)d_ws + 32768);           // 1024*2*352 f32
  float* out  = (float*)d_out;

  combine_weights<<<32, 256, 0, stream>>>(
      (const float*)d_in[4],  (const float*)d_in[5],
      (const float*)d_in[6],  (const float*)d_in[7],
      (const float*)d_in[8],  (const float*)d_in[9],
      (const float*)d_in[10], (const float*)d_in[11],
      (const float*)d_in[12], (const float*)d_in[13],
      (const float*)d_in[14], (const float*)d_in[15],
      (const float*)d_in[16], (const float*)d_in[17],
      (const float*)d_in[18], (const float*)d_in[19],
      wsT, bcw);

  conv_partial<<<2 * M_ * A_, 256, 0, stream>>>(
      image, vectors, feat0, feat1, wsT, bcw, part);

  si_epilogue<<<M_ * A_, 64, 0, stream>>>(
      part, w_si0, w_si1, b_act0, b_act1, out);
}

// Round 8
// 163.514 us; speedup vs baseline: 2.8792x; 1.2661x over previous
//
#include <hip/hip_runtime.h>
#include <math.h>

#define M_ 4
#define A_ 256
#define RBF_ 64
#define F_ 32
#define H_ 32
#define SI_ 32
#define TF_ 128   // 4 tags * F

typedef __attribute__((ext_vector_type(8))) short bf16x8;
typedef __attribute__((ext_vector_type(4))) float f32x4;
typedef __attribute__((ext_vector_type(3))) float f32x3;

__device__ __forceinline__ unsigned short f2bf(float f) {
  union { float f; unsigned u; } v; v.f = f;
  unsigned r = v.u + 0x7FFFu + ((v.u >> 16) & 1u);   // RNE bf16 (weights, one-time)
  return (unsigned short)(r >> 16);
}

// pack two fp32 -> two bf16 (round-half-up: +0x8000 then take hi16) in 3 VALU
__device__ __forceinline__ unsigned pack2bf(float lo, float hi) {
  union { float f; unsigned u; } a, b; a.f = lo; b.f = hi;
  return __builtin_amdgcn_perm(b.u + 0x8000u, a.u + 0x8000u, 0x07060302u);
}

__device__ __forceinline__ float sspf(float x) {
  // log(0.5*exp(x)+0.5) = softplus(x) - ln2, numerically stable
  return fmaxf(x, 0.f) + log1pf(expf(-fabsf(x))) - 0.6931471805599453f;
}

// ---------------------------------------------------------------------------
// Setup: collapse the two linear Dense layers per tag into one 64x32 map.
// ws layout: WcT bf16 [tf=128][k=64] (16384 B) | bc fp32[128] at +16384
//            | part fp32 [1024][2][352] at +32768 (2.88 MB).
// tf = tag*32 + f, tag order {00,01,10,11}.
// ---------------------------------------------------------------------------
__global__ __launch_bounds__(256) void combine_weights(
    const float* __restrict__ w1_00, const float* __restrict__ b1_00,
    const float* __restrict__ w2_00, const float* __restrict__ b2_00,
    const float* __restrict__ w1_01, const float* __restrict__ b1_01,
    const float* __restrict__ w2_01, const float* __restrict__ b2_01,
    const float* __restrict__ w1_10, const float* __restrict__ b1_10,
    const float* __restrict__ w2_10, const float* __restrict__ b2_10,
    const float* __restrict__ w1_11, const float* __restrict__ b1_11,
    const float* __restrict__ w2_11, const float* __restrict__ b2_11,
    unsigned short* __restrict__ wsT, float* __restrict__ bcw)
{
  const float* w1s[4] = {w1_00, w1_01, w1_10, w1_11};
  const float* b1s[4] = {b1_00, b1_01, b1_10, b1_11};
  const float* w2s[4] = {w2_00, w2_01, w2_10, w2_11};
  const float* b2s[4] = {b2_00, b2_01, b2_10, b2_11};
  int tid = blockIdx.x * 256 + threadIdx.x;    // 0..8191
  int k   = tid >> 7;
  int tf  = tid & 127;
  int tag = tf >> 5, f = tf & 31;
  const float* w1 = w1s[tag];
  const float* w2 = w2s[tag];
  float s = 0.f;
  for (int h = 0; h < H_; ++h) s += w1[k * H_ + h] * w2[h * F_ + f];
  wsT[tf * 64 + k] = f2bf(s);                  // transposed for B-frag loads
  if (tid < TF_) {
    const float* b1 = b1s[tag];
    const float* b2 = b2s[tag];
    float sb = b2[f];
    for (int h = 0; h < H_; ++h) sb += b1[h] * w2[h * F_ + f];
    bcw[tf] = sb;                              // bias stays fp32
  }
}

// ---------------------------------------------------------------------------
// Partial-conv kernel: one block per (m,a,half) -- grid 2048, 512 thr, 8 waves.
//  half owns b in [half*128, half*128+128) = 8 b-tiles.
//  WAVE-PER-TAG: wave wu (readfirstlane -> SGPR, uniform branches) owns ONE
//  ct = tag*2+which tf-tile; true live set ~55 VGPR -> no spill (R7 post-
//  mortem: double-buffered 2-ct waves needed ~110 live at a 64 allocation ->
//  62 MB scratch traffic).
//  GEMM via mfma_f32_16x16x32_bf16; C-frag row(b)=quad*4+reg, col=lane&15.
//  vectors staged to LDS (shared across lanes; they were 16x-duplicated
//  global loads); feat1 via dwordx3. Quad-copy reduce via shfl_xor; partials
//  (352 per half) to ws; si_epilogue sums halves.
// LDS: sA [128][72] bf16 (18432) + sV [128*3] f32 (1536) = 19968 B.
// Occupancy: 32-wave/CU cap -> 4 blocks/CU, grid covered in 2 rounds.
// ---------------------------------------------------------------------------
__global__ __launch_bounds__(512, 4) void conv_partial(
    const float* __restrict__ image, const float* __restrict__ vectors,
    const float* __restrict__ feat0, const float* __restrict__ feat1,
    const unsigned short* __restrict__ wsT, const float* __restrict__ bcw,
    float* __restrict__ part)
{
  __shared__ __align__(16) unsigned short sA[128 * 72];   // 18432 B
  __shared__ float sV[128 * 3];                           // 1536 B

  const int t    = threadIdx.x;
  const int bid  = blockIdx.x;
  const int ma   = bid >> 1;        // m*256 + a
  const int half = bid & 1;
  const int m    = ma >> 8;
  const int l    = t & 63;
  const int n    = l & 15;
  const int quad = l >> 4;
  // wave id as SGPR -> uniform branches, scalar addressing
  const int wu    = __builtin_amdgcn_readfirstlane(t >> 6);   // 0..7
  const int which = wu & 1;
  const int tag   = wu >> 1;        // 0:'00' 1:'01' 2:'10' 3:'11'
  const int ct    = tag * 2 + which;
  const int f     = which * 16 + n; // feature column this lane owns

  // ---- Wc fragment + bias into registers (global, L2-resident) ----
  const unsigned short* wr = wsT + (ct * 16 + n) * 64 + quad * 8;
  const bf16x8 w0 = *(const bf16x8*)(wr);
  const bf16x8 w1 = *(const bf16x8*)(wr + 32);
  const float  bc = bcw[ct * 16 + n];

  // ---- stage this half's image rows (128 b x 64 rbf) to LDS as bf16 ----
  const float* imgH = image + ((size_t)ma * A_ + half * 128) * RBF_;
  #pragma unroll
  for (int i = 0; i < 2; ++i) {
    int g = t + 512 * i;            // 0..1023 groups of 8 elems
    int r = g >> 3, c8 = g & 7;
    const float* src = imgH + r * RBF_ + c8 * 8;
    float4 v0 = *(const float4*)(src);
    float4 v1 = *(const float4*)(src + 4);
    uint4 pk;
    pk.x = pack2bf(v0.x, v0.y);
    pk.y = pack2bf(v0.z, v0.w);
    pk.z = pack2bf(v1.x, v1.y);
    pk.w = pack2bf(v1.z, v1.w);
    *(uint4*)&sA[r * 72 + c8 * 8] = pk;
  }
  // ---- stage vectors (128 b x 3) to LDS ----
  if (t < 384) sV[t] = vectors[((size_t)ma * A_ + half * 128) * 3 + t];
  __syncthreads();

  // lane-private feat pointers (global b)
  const float* p0 = feat0 + (size_t)(m * A_) * F_ + f;          // + b*F_
  const float* p1 = feat1 + ((size_t)(m * A_) * F_ + f) * 3;    // + b*96

  float pA = 0.f, pB0 = 0.f, pB1 = 0.f, pB2 = 0.f;

  #pragma unroll 1
  for (int bt = 0; bt < 8; ++bt) {
    const int brow = bt * 16;
    const int lb   = brow + quad * 4;        // local b of acc row r=0
    const int b0   = half * 128 + lb;        // global b

    // operand loads for this tile (uniform branches; short live ranges)
    float ft0[4];
    f32x3 gv[4];
    if (tag <= 1) {
      #pragma unroll
      for (int r = 0; r < 4; ++r) ft0[r] = p0[(b0 + r) * F_];
    }
    if (tag >= 2) {
      #pragma unroll
      for (int r = 0; r < 4; ++r) gv[r] = *(const f32x3*)&p1[(size_t)(b0 + r) * (F_ * 3)];
    }

    // A-frags + GEMM for this tile
    const bf16x8 a0 = *(const bf16x8*)&sA[(brow + n) * 72 + quad * 8];
    const bf16x8 a1 = *(const bf16x8*)&sA[(brow + n) * 72 + 32 + quad * 8];
    f32x4 acc = {bc, bc, bc, bc};
    acc = __builtin_amdgcn_mfma_f32_16x16x32_bf16(a0, w0, acc, 0, 0, 0);
    acc = __builtin_amdgcn_mfma_f32_16x16x32_bf16(a1, w1, acc, 0, 0, 0);

    // contraction (tag-uniform)
    if (tag == 0) {            // out_0x0_0
      #pragma unroll
      for (int r = 0; r < 4; ++r) pA += acc[r] * ft0[r];
    } else if (tag == 1) {     // out_0x1_1 = v * (R*feat0)
      #pragma unroll
      for (int r = 0; r < 4; ++r) {
        const float s  = acc[r] * ft0[r];
        const float vx = sV[(lb + r) * 3 + 0];
        const float vy = sV[(lb + r) * 3 + 1];
        const float vz = sV[(lb + r) * 3 + 2];
        pB0 += vx * s; pB1 += vy * s; pB2 += vz * s;
      }
    } else if (tag == 2) {     // out_1x0_1 = R * feat1
      #pragma unroll
      for (int r = 0; r < 4; ++r) {
        const float Rr = acc[r];
        pB0 += Rr * gv[r][0]; pB1 += Rr * gv[r][1]; pB2 += Rr * gv[r][2];
      }
    } else {                   // out_1x1_0 (dot) + out_1x1_1 (cross)
      #pragma unroll
      for (int r = 0; r < 4; ++r) {
        const float Rr = acc[r];
        const float gx = gv[r][0], gy = gv[r][1], gz = gv[r][2];
        const float vx = sV[(lb + r) * 3 + 0];
        const float vy = sV[(lb + r) * 3 + 1];
        const float vz = sV[(lb + r) * 3 + 2];
        pA  += Rr * (vx * gx + vy * gy + vz * gz);
        pB0 += Rr * (vy * gz - vz * gy);
        pB1 += Rr * (vz * gx - vx * gz);
        pB2 += Rr * (vx * gy - vy * gx);
      }
    }
  }

  // ---- reduce the 4 quad-copies via cross-lane butterfly, write partials ----
#define QRED(x) { x += __shfl_xor(x, 16); x += __shfl_xor(x, 32); }
  QRED(pA) QRED(pB0) QRED(pB1) QRED(pB2)
  if (quad == 0) {
    float* dst = part + ((size_t)ma * 2 + half) * 352;
    // slots (cat order): out000: f | out110: 32+f | out011: 64+f*3+d
    //                    out101: 160+f*3+d | out111: 256+f*3+d
    if (tag == 0) {
      dst[f] = pA;
    } else if (tag == 1) {
      f32x3 v = {pB0, pB1, pB2};
      *(f32x3*)&dst[64 + f * 3] = v;
    } else if (tag == 2) {
      f32x3 v = {pB0, pB1, pB2};
      *(f32x3*)&dst[160 + f * 3] = v;
    } else {
      dst[32 + f] = pA;
      f32x3 v = {pB0, pB1, pB2};
      *(f32x3*)&dst[256 + f * 3] = v;
    }
  }
}

// ---------------------------------------------------------------------------
// Epilogue: one block per (m,a), 64 threads. Sum the two halves' partials,
// then self-interaction + equivariant activation.
// ---------------------------------------------------------------------------
__global__ __launch_bounds__(64) void si_epilogue(
    const float* __restrict__ part,
    const float* __restrict__ w_si0, const float* __restrict__ w_si1,
    const float* __restrict__ b_act0, const float* __restrict__ b_act1,
    float* __restrict__ out)
{
  __shared__ float cat[352];
  const int ma = blockIdx.x;
  const int t  = threadIdx.x;
  const float* pA = part + (size_t)ma * 704;
  const float* pB = pA + 352;
  for (int s = t; s < 352; s += 64) cat[s] = pA[s] + pB[s];
  __syncthreads();

  const int outBase = ma * SI_;
  if (t < 32) {
    const float* wr = w_si0 + t * 64;
    float s = 0.f;
    #pragma unroll 8
    for (int ff = 0; ff < 64; ++ff) s += cat[ff] * wr[ff];
    s += b_act0[t];
    out[outBase + t] = sspf(s);
  } else {
    int g = t - 32;
    const float* wr = w_si1 + g * 96;
    float s0 = 0.f, s1 = 0.f, s2 = 0.f;
    #pragma unroll 8
    for (int ff = 0; ff < 96; ++ff) {
      float wv = wr[ff];
      s0 += cat[64 + ff * 3 + 0] * wv;
      s1 += cat[64 + ff * 3 + 1] * wv;
      s2 += cat[64 + ff * 3 + 2] * wv;
    }
    float n2 = s0 * s0 + s1 * s1 + s2 * s2;
    float n1 = sqrtf(fmaxf(n2, 1e-7f));     // norm_with_epsilon, EPS=1e-7
    float a1 = sspf(n1 + b_act1[g]);
    float sc = a1 / n1;
    int ob = M_ * A_ * SI_ + (outBase + g) * 3;   // o0 is 32768 floats
    out[ob + 0] = s0 * sc;
    out[ob + 1] = s1 * sc;
    out[ob + 2] = s2 * sc;
  }
}

extern "C" void kernel_launch(void* const* d_in, const int* in_sizes, int n_in,
                              void* d_out, int out_size, void* d_ws, size_t ws_size,
                              hipStream_t stream) {
  const float* image   = (const float*)d_in[0];
  const float* vectors = (const float*)d_in[1];
  const float* feat0   = (const float*)d_in[2];
  const float* feat1   = (const float*)d_in[3];
  const float* w_si0   = (const float*)d_in[20];
  const float* w_si1   = (const float*)d_in[21];
  const float* b_act0  = (const float*)d_in[22];
  const float* b_act1  = (const float*)d_in[23];
  unsigned short* wsT = (unsigned short*)d_ws;           // 128*64 bf16 = 16384 B
  float* bcw  = (float*)((char*)d_ws + 16384);           // 128 f32
  float* part = (float*)((char*)d_ws + 32768);           // 1024*2*352 f32
  float* out  = (float*)d_out;

  combine_weights<<<32, 256, 0, stream>>>(
      (const float*)d_in[4],  (const float*)d_in[5],
      (const float*)d_in[6],  (const float*)d_in[7],
      (const float*)d_in[8],  (const float*)d_in[9],
      (const float*)d_in[10], (const float*)d_in[11],
      (const float*)d_in[12], (const float*)d_in[13],
      (const float*)d_in[14], (const float*)d_in[15],
      (const float*)d_in[16], (const float*)d_in[17],
      (const float*)d_in[18], (const float*)d_in[19],
      wsT, bcw);

  conv_partial<<<2 * M_ * A_, 512, 0, stream>>>(
      image, vectors, feat0, feat1, wsT, bcw, part);

  si_epilogue<<<M_ * A_, 64, 0, stream>>>(
      part, w_si0, w_si1, b_act0, b_act1, out);
}